// Round 3
// baseline (1010.394 us; speedup 1.0000x reference)
//
#include <hip/hip_runtime.h>
#include <math.h>

#define BB 64
#define CC 2048
#define MM 196
#define DD 256
#define NTOT (BB * MM)  // 12544

// ---------------------------------------------------------------------------
// K1: 1x1 conv + BN(eval) + ReLU.  GEMM: W[256x2048] * X[b][2048x196].
// 64x64 tiles -> 784 blocks (3 blocks/CU, 12 waves/CU) for latency hiding;
// 256 threads, 4x4/thread, KC=32, register prefetch of next K-chunk.
// Output TRANSPOSED: yt[b][m][d].
// ---------------------------------------------------------------------------
__global__ __launch_bounds__(256) void k_conv(
    const float* __restrict__ x, const float* __restrict__ w,
    const float* __restrict__ gamma, const float* __restrict__ beta,
    const float* __restrict__ rmean, const float* __restrict__ rvar,
    float* __restrict__ yt) {
  const int tid = threadIdx.x;
  const int tx = tid & 15;  // n-group
  const int ty = tid >> 4;  // d-group
  const int n0 = blockIdx.x * 64;
  const int d0 = blockIdx.y * 64;

  __shared__ float Ws[32][66];  // [k][d], stride 66 -> 2-way (free)
  __shared__ float Xs[32][64];  // [k][n]

  float acc[4][4];
#pragma unroll
  for (int i = 0; i < 4; ++i)
#pragma unroll
    for (int j = 0; j < 4; ++j) acc[i][j] = 0.f;

  // staging assignments
  const int cW = tid & 31;  // k within chunk for W
  const int dW = tid >> 5;  // d base (+8p)
  const int nX = tid & 63;  // n within tile
  const int kX = tid >> 6;  // k base (+4p)
  const int gn = n0 + nX;
  const int bX = gn / MM;
  const int mX = gn - bX * MM;
  const float* xptr = x + (size_t)bX * CC * MM + mX;

  float wreg[8], xreg[8];
#pragma unroll
  for (int p = 0; p < 8; ++p)
    wreg[p] = w[(size_t)(d0 + dW + p * 8) * CC + cW];
#pragma unroll
  for (int p = 0; p < 8; ++p)
    xreg[p] = xptr[(size_t)(kX + p * 4) * MM];

  for (int k0 = 0; k0 < CC; k0 += 32) {
    __syncthreads();
#pragma unroll
    for (int p = 0; p < 8; ++p) Ws[cW][dW + p * 8] = wreg[p];
#pragma unroll
    for (int p = 0; p < 8; ++p) Xs[kX + p * 4][nX] = xreg[p];
    __syncthreads();
    if (k0 + 32 < CC) {  // prefetch next chunk
#pragma unroll
      for (int p = 0; p < 8; ++p)
        wreg[p] = w[(size_t)(d0 + dW + p * 8) * CC + (k0 + 32) + cW];
#pragma unroll
      for (int p = 0; p < 8; ++p)
        xreg[p] = xptr[(size_t)(k0 + 32 + kX + p * 4) * MM];
    }
#pragma unroll
    for (int k = 0; k < 32; ++k) {
      float a[4], bv[4];
#pragma unroll
      for (int i = 0; i < 4; ++i) a[i] = Ws[k][ty * 4 + i];
#pragma unroll
      for (int j = 0; j < 4; ++j) bv[j] = Xs[k][tx * 4 + j];
#pragma unroll
      for (int i = 0; i < 4; ++i)
#pragma unroll
        for (int j = 0; j < 4; ++j) acc[i][j] = fmaf(a[i], bv[j], acc[i][j]);
    }
  }

  // BN (eval) + ReLU epilogue, store transposed yt[b][m][d]
  float scl[4], sft[4];
#pragma unroll
  for (int i = 0; i < 4; ++i) {
    int d = d0 + ty * 4 + i;
    float s = gamma[d] / sqrtf(rvar[d] + 1e-5f);
    scl[i] = s;
    sft[i] = beta[d] - rmean[d] * s;
  }
#pragma unroll
  for (int j = 0; j < 4; ++j) {
    int n = n0 + tx * 4 + j;
    int b = n / MM;
    int m = n - b * MM;
    float* yrow = yt + ((size_t)b * MM + m) * DD + d0 + ty * 4;
#pragma unroll
    for (int i = 0; i < 4; ++i) {
      float v = fmaf(acc[i][j], scl[i], sft[i]);
      yrow[i] = v > 0.f ? v : 0.f;
    }
  }
}

// ---------------------------------------------------------------------------
// K2: per-(b,d) mean over m in fp64.  yt is d-contiguous -> coalesced.
// ---------------------------------------------------------------------------
__global__ __launch_bounds__(256) void k_means(const float* __restrict__ yt,
                                               double* __restrict__ mean) {
  const int b = blockIdx.x;
  const int d = threadIdx.x;
  const float* p = yt + (size_t)b * MM * DD + d;
  double s0 = 0, s1 = 0, s2 = 0, s3 = 0;
  for (int m = 0; m < MM; m += 4) {
    s0 += (double)p[(size_t)(m + 0) * DD];
    s1 += (double)p[(size_t)(m + 1) * DD];
    s2 += (double)p[(size_t)(m + 2) * DD];
    s3 += (double)p[(size_t)(m + 3) * DD];
  }
  mean[b * DD + d] = (s0 + s1 + s2 + s3) * (1.0 / MM);
}

// ---------------------------------------------------------------------------
// K3: cov[b] = (Y-mu)(Y-mu)^T / M + eps*I  in fp64.  Lower 64x64 tiles only,
// mirrored on store.  256 thr, 4x4 fp64 per thread, KC=32.
// ---------------------------------------------------------------------------
__global__ __launch_bounds__(256) void k_cov(const float* __restrict__ yt,
                                             const double* __restrict__ mean,
                                             double* __restrict__ cov) {
  const int b = blockIdx.x;
  const int t = blockIdx.y;  // 0..9 -> (ti >= tj)
  const int ti = (t < 1) ? 0 : (t < 3) ? 1 : (t < 6) ? 2 : 3;
  const int tj = t - (ti * (ti + 1)) / 2;
  const int i0 = ti * 64, j0 = tj * 64;
  const int tid = threadIdx.x;
  const int tx = tid & 15, ty = tid >> 4;

  __shared__ double As[32][66];
  __shared__ double Bs[32][66];

  double acc[4][4];
#pragma unroll
  for (int i = 0; i < 4; ++i)
#pragma unroll
    for (int j = 0; j < 4; ++j) acc[i][j] = 0.0;

  const int dl = tid & 63, kl = tid >> 6;
  const double mA = mean[b * DD + i0 + dl];
  const double mB = mean[b * DD + j0 + dl];
  const float* ybase = yt + (size_t)b * MM * DD;

  for (int k0 = 0; k0 < MM; k0 += 32) {
    __syncthreads();
#pragma unroll
    for (int p = 0; p < 8; ++p) {
      int k = kl + p * 4;
      int m = k0 + k;
      double av = 0.0, bv = 0.0;
      if (m < MM) {
        av = (double)ybase[(size_t)m * DD + i0 + dl] - mA;
        bv = (double)ybase[(size_t)m * DD + j0 + dl] - mB;
      }
      As[k][dl] = av;
      Bs[k][dl] = bv;
    }
    __syncthreads();
#pragma unroll
    for (int k = 0; k < 32; ++k) {
      double a[4], bv[4];
#pragma unroll
      for (int i = 0; i < 4; ++i) a[i] = As[k][ty * 4 + i];
#pragma unroll
      for (int j = 0; j < 4; ++j) bv[j] = Bs[k][tx * 4 + j];
#pragma unroll
      for (int i = 0; i < 4; ++i)
#pragma unroll
        for (int j = 0; j < 4; ++j) acc[i][j] = fma(a[i], bv[j], acc[i][j]);
    }
  }

  double* cb = cov + (size_t)b * DD * DD;
#pragma unroll
  for (int i = 0; i < 4; ++i) {
#pragma unroll
    for (int j = 0; j < 4; ++j) {
      int gi = i0 + ty * 4 + i, gj = j0 + tx * 4 + j;
      double v = acc[i][j] * (1.0 / MM);
      if (gi == gj) v += 1e-6;
      cb[(size_t)gi * DD + gj] = v;
      if (ti != tj) cb[(size_t)gj * DD + gi] = v;
    }
  }
}

// ---------------------------------------------------------------------------
// K4: FUSED blocked Cholesky (lower), one block per matrix, ONE launch.
// Per 32-panel: [waves 1..3 stage A21 -> LDS | lanes<32 factor 32x32 diag in
// registers via __shfl, zero barriers] -> barrier -> register TRSM (each
// thread one row, zero barriers; result kept in LDS) -> barrier ->
// trailing A22 -= L21*L21^T as 64x64 tiles, 4x4/thread, global RMW.
// ~3 barriers/panel vs 64 in the R1 version; no inter-launch gaps.
// ---------------------------------------------------------------------------
__global__ __launch_bounds__(256) void k_cholf(double* __restrict__ cov) {
  const int b = blockIdx.x;
  double* A = cov + (size_t)b * DD * DD;
  const int tid = threadIdx.x;

  __shared__ double Ps[224][33];  // A21 / L21 rows (max T = 224)
  __shared__ double L11s[32][33];
  __shared__ double rpivs[32];

  for (int kb = 0; kb < 8; ++kb) {
    const int j0 = kb * 32;
    const int T = DD - j0 - 32;

    if (tid >= 64) {
      // waves 1..3: stage A21 into LDS (coalesced rows)
      for (int e = tid - 64; e < T * 32; e += 192) {
        int r = e >> 5, c = e & 31;
        Ps[r][c] = A[(size_t)(j0 + 32 + r) * DD + j0 + c];
      }
    } else if (tid < 32) {
      // diag block factor in registers, wave-synchronous
      double r[32];
#pragma unroll
      for (int k = 0; k < 32; ++k) r[k] = A[(size_t)(j0 + tid) * DD + j0 + k];
      double rpkeep = 0.0;
#pragma unroll
      for (int j = 0; j < 32; ++j) {
        double dj = __shfl(r[j], j);
        double piv = sqrt(dj);
        double rp = 1.0 / piv;
        if (tid == j) {
          r[j] = piv;
          rpkeep = rp;
        } else {
          r[j] = r[j] * rp;  // lanes < j update junk; harmless
        }
        double lij = r[j];
#pragma unroll
        for (int k = j + 1; k < 32; ++k) {
          double ck = __shfl(lij, k);
          r[k] -= lij * ck;
        }
      }
#pragma unroll
      for (int k = 0; k < 32; ++k) L11s[tid][k] = (k <= tid) ? r[k] : 0.0;
      rpivs[tid] = rpkeep;
      for (int k = 0; k <= tid; ++k) A[(size_t)(j0 + tid) * DD + j0 + k] = r[k];
    }
    __syncthreads();

    // TRSM: each thread owns one row of L21 in registers
    if (tid < T) {
      double q[32];
#pragma unroll
      for (int k = 0; k < 32; ++k) q[k] = Ps[tid][k];
#pragma unroll
      for (int j = 0; j < 32; ++j) {
        double s = q[j];
#pragma unroll
        for (int k = 0; k < 32; ++k)
          if (k < j) s -= q[k] * L11s[j][k];
        q[j] = s * rpivs[j];
      }
      double* dst = &A[(size_t)(j0 + 32 + tid) * DD + j0];
#pragma unroll
      for (int k = 0; k < 32; ++k) {
        dst[k] = q[k];
        Ps[tid][k] = q[k];  // keep L21 in LDS for the trailing update
      }
    }
    __syncthreads();

    // trailing update: A22 -= L21 * L21^T, 64x64 lower tiles, 4x4/thread
    if (T > 0) {
      const int nt = (T + 63) >> 6;
      const int txl = tid & 15, tyl = tid >> 4;
      for (int tI = 0; tI < nt; ++tI)
        for (int tJ = 0; tJ <= tI; ++tJ) {
          const int bi = tI * 64 + tyl * 4;
          const int bj = tJ * 64 + txl * 4;
          int ri[4], rj[4];
#pragma unroll
          for (int q = 0; q < 4; ++q) {
            ri[q] = (bi + q < T) ? bi + q : T - 1;  // clamp; store-guarded
            rj[q] = (bj + q < T) ? bj + q : T - 1;
          }
          double s[4][4];
#pragma unroll
          for (int i = 0; i < 4; ++i)
#pragma unroll
            for (int j = 0; j < 4; ++j) s[i][j] = 0.0;
#pragma unroll
          for (int p = 0; p < 32; ++p) {
            double a[4], bv[4];
#pragma unroll
            for (int i = 0; i < 4; ++i) a[i] = Ps[ri[i]][p];
#pragma unroll
            for (int j = 0; j < 4; ++j) bv[j] = Ps[rj[j]][p];
#pragma unroll
            for (int i = 0; i < 4; ++i)
#pragma unroll
              for (int j = 0; j < 4; ++j) s[i][j] = fma(a[i], bv[j], s[i][j]);
          }
#pragma unroll
          for (int i = 0; i < 4; ++i)
#pragma unroll
            for (int j = 0; j < 4; ++j) {
              int gi = bi + i, gj = bj + j;
              if (gi < T && gj < T && gi >= gj)
                A[(size_t)(j0 + 32 + gi) * DD + (j0 + 32 + gj)] -= s[i][j];
            }
        }
    }
    __syncthreads();  // trailing RMW + Ps reads done before next panel
  }
}

// ---------------------------------------------------------------------------
// K5: out[b, triu(i,j)] = (i==j) ? 2*log(L[ii]) : L[j][i], fp32.
// Coalesced: stage a 64x64 tile of L^T via LDS (reads contiguous in i),
// then write contiguous runs of each output row.
// ---------------------------------------------------------------------------
__global__ __launch_bounds__(256) void k_out(const double* __restrict__ cov,
                                             float* __restrict__ out) {
  const int b = blockIdx.y;
  int t = blockIdx.x;  // 0..9 -> (ti <= tj) upper tiles
  int ti = 0, tj = t;
  while (tj >= 4 - ti) {
    tj -= (4 - ti);
    ti++;
  }
  tj += ti;
  const int tid = threadIdx.x;
  const double* A = cov + (size_t)b * DD * DD;

  __shared__ float S[64][65];
  for (int e = tid; e < 4096; e += 256) {
    int jj = e >> 6, ii = e & 63;  // ii contiguous -> coalesced global read
    S[jj][ii] = (float)A[(size_t)(tj * 64 + jj) * DD + ti * 64 + ii];
  }
  __syncthreads();

  for (int e = tid; e < 4096; e += 256) {
    int ii = e >> 6, jj = e & 63;  // jj contiguous -> coalesced store
    int i = ti * 64 + ii, j = tj * 64 + jj;
    if (j < i) continue;
    float v = S[jj][ii];
    if (i == j) v = 2.0f * logf(v);
    int off = i * DD - (i * (i - 1)) / 2 + (j - i);
    out[(size_t)b * 32896 + off] = v;
  }
}

extern "C" void kernel_launch(void* const* d_in, const int* in_sizes, int n_in,
                              void* d_out, int out_size, void* d_ws,
                              size_t ws_size, hipStream_t stream) {
  const float* x = (const float*)d_in[0];
  const float* w = (const float*)d_in[1];
  const float* gamma = (const float*)d_in[2];
  const float* beta = (const float*)d_in[3];
  const float* rmean = (const float*)d_in[4];
  const float* rvar = (const float*)d_in[5];
  float* out = (float*)d_out;

  char* ws = (char*)d_ws;
  float* yt = (float*)ws;                           // 64*196*256*4 = 12,845,056 B
  double* mean = (double*)(ws + 12845056);          // 64*256*8     =    131,072 B
  double* cov = (double*)(ws + 12845056 + 131072);  // 64*256*256*8 = 33,554,432 B

  k_conv<<<dim3(NTOT / 64, DD / 64), 256, 0, stream>>>(x, w, gamma, beta,
                                                       rmean, rvar, yt);
  k_means<<<BB, 256, 0, stream>>>(yt, mean);
  k_cov<<<dim3(BB, 10), 256, 0, stream>>>(yt, mean, cov);
  k_cholf<<<BB, 256, 0, stream>>>(cov);
  k_out<<<dim3(10, BB), 256, 0, stream>>>(cov, out);
}

// Round 4
// 720.427 us; speedup vs baseline: 1.4025x; 1.4025x over previous
//
#include <hip/hip_runtime.h>
#include <math.h>

#define BB 64
#define CC 2048
#define MM 196
#define DD 256
#define NTOT (BB * MM)  // 12544

// ---------------------------------------------------------------------------
// K1: 1x1 conv + BN(eval) + ReLU.  GEMM: W[256x2048] * X[b][2048x196].
// 64x64 tiles -> 784 blocks, 256 threads, 4x4/thread, KC=32, reg prefetch.
// Output TRANSPOSED: yt[b][m][d].
// ---------------------------------------------------------------------------
__global__ __launch_bounds__(256) void k_conv(
    const float* __restrict__ x, const float* __restrict__ w,
    const float* __restrict__ gamma, const float* __restrict__ beta,
    const float* __restrict__ rmean, const float* __restrict__ rvar,
    float* __restrict__ yt) {
  const int tid = threadIdx.x;
  const int tx = tid & 15;
  const int ty = tid >> 4;
  const int n0 = blockIdx.x * 64;
  const int d0 = blockIdx.y * 64;

  __shared__ float Ws[32][66];
  __shared__ float Xs[32][64];

  float acc[4][4];
#pragma unroll
  for (int i = 0; i < 4; ++i)
#pragma unroll
    for (int j = 0; j < 4; ++j) acc[i][j] = 0.f;

  const int cW = tid & 31;
  const int dW = tid >> 5;
  const int nX = tid & 63;
  const int kX = tid >> 6;
  const int gn = n0 + nX;
  const int bX = gn / MM;
  const int mX = gn - bX * MM;
  const float* xptr = x + (size_t)bX * CC * MM + mX;

  float wreg[8], xreg[8];
#pragma unroll
  for (int p = 0; p < 8; ++p)
    wreg[p] = w[(size_t)(d0 + dW + p * 8) * CC + cW];
#pragma unroll
  for (int p = 0; p < 8; ++p)
    xreg[p] = xptr[(size_t)(kX + p * 4) * MM];

  for (int k0 = 0; k0 < CC; k0 += 32) {
    __syncthreads();
#pragma unroll
    for (int p = 0; p < 8; ++p) Ws[cW][dW + p * 8] = wreg[p];
#pragma unroll
    for (int p = 0; p < 8; ++p) Xs[kX + p * 4][nX] = xreg[p];
    __syncthreads();
    if (k0 + 32 < CC) {
#pragma unroll
      for (int p = 0; p < 8; ++p)
        wreg[p] = w[(size_t)(d0 + dW + p * 8) * CC + (k0 + 32) + cW];
#pragma unroll
      for (int p = 0; p < 8; ++p)
        xreg[p] = xptr[(size_t)(k0 + 32 + kX + p * 4) * MM];
    }
#pragma unroll
    for (int k = 0; k < 32; ++k) {
      float a[4], bv[4];
#pragma unroll
      for (int i = 0; i < 4; ++i) a[i] = Ws[k][ty * 4 + i];
#pragma unroll
      for (int j = 0; j < 4; ++j) bv[j] = Xs[k][tx * 4 + j];
#pragma unroll
      for (int i = 0; i < 4; ++i)
#pragma unroll
        for (int j = 0; j < 4; ++j) acc[i][j] = fmaf(a[i], bv[j], acc[i][j]);
    }
  }

  float scl[4], sft[4];
#pragma unroll
  for (int i = 0; i < 4; ++i) {
    int d = d0 + ty * 4 + i;
    float s = gamma[d] / sqrtf(rvar[d] + 1e-5f);
    scl[i] = s;
    sft[i] = beta[d] - rmean[d] * s;
  }
#pragma unroll
  for (int j = 0; j < 4; ++j) {
    int n = n0 + tx * 4 + j;
    int b = n / MM;
    int m = n - b * MM;
    float* yrow = yt + ((size_t)b * MM + m) * DD + d0 + ty * 4;
#pragma unroll
    for (int i = 0; i < 4; ++i) {
      float v = fmaf(acc[i][j], scl[i], sft[i]);
      yrow[i] = v > 0.f ? v : 0.f;
    }
  }
}

// ---------------------------------------------------------------------------
// K2: per-(b,d) mean over m in fp64.
// ---------------------------------------------------------------------------
__global__ __launch_bounds__(256) void k_means(const float* __restrict__ yt,
                                               double* __restrict__ mean) {
  const int b = blockIdx.x;
  const int d = threadIdx.x;
  const float* p = yt + (size_t)b * MM * DD + d;
  double s0 = 0, s1 = 0, s2 = 0, s3 = 0;
  for (int m = 0; m < MM; m += 4) {
    s0 += (double)p[(size_t)(m + 0) * DD];
    s1 += (double)p[(size_t)(m + 1) * DD];
    s2 += (double)p[(size_t)(m + 2) * DD];
    s3 += (double)p[(size_t)(m + 3) * DD];
  }
  mean[b * DD + d] = (s0 + s1 + s2 + s3) * (1.0 / MM);
}

// ---------------------------------------------------------------------------
// K3: cov[b] = (Y-mu)(Y-mu)^T / M + eps*I  in fp64, lower tiles mirrored.
// ---------------------------------------------------------------------------
__global__ __launch_bounds__(256) void k_cov(const float* __restrict__ yt,
                                             const double* __restrict__ mean,
                                             double* __restrict__ cov) {
  const int b = blockIdx.x;
  const int t = blockIdx.y;
  const int ti = (t < 1) ? 0 : (t < 3) ? 1 : (t < 6) ? 2 : 3;
  const int tj = t - (ti * (ti + 1)) / 2;
  const int i0 = ti * 64, j0 = tj * 64;
  const int tid = threadIdx.x;
  const int tx = tid & 15, ty = tid >> 4;

  __shared__ double As[32][66];
  __shared__ double Bs[32][66];

  double acc[4][4];
#pragma unroll
  for (int i = 0; i < 4; ++i)
#pragma unroll
    for (int j = 0; j < 4; ++j) acc[i][j] = 0.0;

  const int dl = tid & 63, kl = tid >> 6;
  const double mA = mean[b * DD + i0 + dl];
  const double mB = mean[b * DD + j0 + dl];
  const float* ybase = yt + (size_t)b * MM * DD;

  for (int k0 = 0; k0 < MM; k0 += 32) {
    __syncthreads();
#pragma unroll
    for (int p = 0; p < 8; ++p) {
      int k = kl + p * 4;
      int m = k0 + k;
      double av = 0.0, bv = 0.0;
      if (m < MM) {
        av = (double)ybase[(size_t)m * DD + i0 + dl] - mA;
        bv = (double)ybase[(size_t)m * DD + j0 + dl] - mB;
      }
      As[k][dl] = av;
      Bs[k][dl] = bv;
    }
    __syncthreads();
#pragma unroll
    for (int k = 0; k < 32; ++k) {
      double a[4], bv[4];
#pragma unroll
      for (int i = 0; i < 4; ++i) a[i] = As[k][ty * 4 + i];
#pragma unroll
      for (int j = 0; j < 4; ++j) bv[j] = Bs[k][tx * 4 + j];
#pragma unroll
      for (int i = 0; i < 4; ++i)
#pragma unroll
        for (int j = 0; j < 4; ++j) acc[i][j] = fma(a[i], bv[j], acc[i][j]);
    }
  }

  double* cb = cov + (size_t)b * DD * DD;
#pragma unroll
  for (int i = 0; i < 4; ++i) {
#pragma unroll
    for (int j = 0; j < 4; ++j) {
      int gi = i0 + ty * 4 + i, gj = j0 + tx * 4 + j;
      double v = acc[i][j] * (1.0 / MM);
      if (gi == gj) v += 1e-6;
      cb[(size_t)gi * DD + gj] = v;
      if (ti != tj) cb[(size_t)gj * DD + gi] = v;
    }
  }
}

// ---------------------------------------------------------------------------
// K4: lookahead Cholesky step kb.  grid = (BB, 1 + tiles(kb)).
//  block y==0: apply panel(kb-1) update to the 32-col strip of panel kb
//    (in LDS), factor 32x32 diag (shfl, zero barriers), register TRSM for
//    rows below; write L panel to global.
//  blocks y>=1: apply panel(kb-1) update to one 64x64 lower tile of the
//    region cols >= j0+32, reading L21(kb-1) from global (previous launch).
// Every entry (r,c), c in panel q, gets update p=q-1 from P(q) block 0 and
// updates p<q-1 from P(p+1) siblings -> each applied exactly once, in order.
// ---------------------------------------------------------------------------
__global__ __launch_bounds__(256) void k_panel2(double* __restrict__ cov,
                                                int kb) {
  const int b = blockIdx.x;
  double* A = cov + (size_t)b * DD * DD;
  const int j0 = kb * 32;
  const int tid = threadIdx.x;

  __shared__ double Sp[256][33];   // strip rows [j0,256) x 32 cols
  __shared__ double Lp[224][33];   // L21(kb-1) rows [j0,256) (block0) / tiles
  __shared__ double L11s[32][33];
  __shared__ double rpivs[32];

  if (blockIdx.y == 0) {
    const int R = DD - j0;   // strip rows
    const int pj = j0 - 32;  // previous panel col base

    // stage strip (and L21(kb-1) if any), coalesced
    for (int e = tid; e < R * 32; e += 256) {
      int r = e >> 5, c = e & 31;
      Sp[r][c] = A[(size_t)(j0 + r) * DD + j0 + c];
      if (kb > 0) Lp[r][c] = A[(size_t)(j0 + r) * DD + pj + c];
    }
    __syncthreads();

    // strip update: Sp[r][c] -= dot(Lp[r], Lp[c])  (upper junk harmless)
    if (kb > 0) {
      const int cg = tid & 7;   // 4 cols each
      const int rg = tid >> 3;  // rows rg, rg+32, ...
      const int c0 = cg * 4;
      for (int r = rg; r < R; r += 32) {
        double a0 = 0, a1 = 0, a2 = 0, a3 = 0;
#pragma unroll
        for (int p = 0; p < 32; ++p) {
          double lr = Lp[r][p];
          a0 = fma(lr, Lp[c0 + 0][p], a0);
          a1 = fma(lr, Lp[c0 + 1][p], a1);
          a2 = fma(lr, Lp[c0 + 2][p], a2);
          a3 = fma(lr, Lp[c0 + 3][p], a3);
        }
        Sp[r][c0 + 0] -= a0;
        Sp[r][c0 + 1] -= a1;
        Sp[r][c0 + 2] -= a2;
        Sp[r][c0 + 3] -= a3;
      }
    }
    __syncthreads();

    // 32x32 diag factor in registers (lanes 0..31), zero barriers
    if (tid < 32) {
      double r[32];
#pragma unroll
      for (int k = 0; k < 32; ++k) r[k] = Sp[tid][k];
      double rpkeep = 0.0;
#pragma unroll
      for (int j = 0; j < 32; ++j) {
        double dj = __shfl(r[j], j);
        double piv = sqrt(dj);
        double rp = 1.0 / piv;
        if (tid == j) {
          r[j] = piv;
          rpkeep = rp;
        } else {
          r[j] = r[j] * rp;  // lanes < j update junk; harmless
        }
        double lij = r[j];
#pragma unroll
        for (int k = j + 1; k < 32; ++k) {
          double ck = __shfl(lij, k);
          r[k] -= lij * ck;
        }
      }
#pragma unroll
      for (int k = 0; k < 32; ++k) L11s[tid][k] = (k <= tid) ? r[k] : 0.0;
      rpivs[tid] = rpkeep;
      for (int k = 0; k <= tid; ++k)
        A[(size_t)(j0 + tid) * DD + j0 + k] = r[k];
    }
    __syncthreads();

    // TRSM: thread t owns row j0+32+t in registers; zero barriers
    const int T = R - 32;
    if (tid < T) {
      double q[32];
#pragma unroll
      for (int k = 0; k < 32; ++k) q[k] = Sp[32 + tid][k];
#pragma unroll
      for (int j = 0; j < 32; ++j) {
        double s = q[j];
#pragma unroll
        for (int k = 0; k < 32; ++k)
          if (k < j) s -= q[k] * L11s[j][k];
        q[j] = s * rpivs[j];
      }
      double* dst = &A[(size_t)(j0 + 32 + tid) * DD + j0];
#pragma unroll
      for (int k = 0; k < 32; ++k) dst[k] = q[k];
    }
  } else {
    // sibling: 64x64 lower tile of trailing region cols >= j0+32,
    // rank-32 update with L21(kb-1) read from global (prev launch)
    const int o = j0 + 32;
    const int S = DD - o;
    const int pj = j0 - 32;
    int tI = 0, tJ = (int)blockIdx.y - 1;
    while (tJ > tI) {
      tJ -= (tI + 1);
      tI++;
    }
    const int i0 = tI * 64, jj0 = tJ * 64;
    const int tx = tid & 15, ty = tid >> 4;

    double(*Ea)[33] = (double(*)[33])(&Lp[0][0]);
    double(*Eb)[33] = (double(*)[33])(&Lp[64][0]);

    for (int e = tid; e < 64 * 32; e += 256) {
      int r = e >> 5, c = e & 31;
      Ea[r][c] =
          (i0 + r < S) ? A[(size_t)(o + i0 + r) * DD + pj + c] : 0.0;
      Eb[r][c] =
          (jj0 + r < S) ? A[(size_t)(o + jj0 + r) * DD + pj + c] : 0.0;
    }
    __syncthreads();

    double s[4][4];
#pragma unroll
    for (int i = 0; i < 4; ++i)
#pragma unroll
      for (int j = 0; j < 4; ++j) s[i][j] = 0.0;

    const int bi = ty * 4, bj = tx * 4;
#pragma unroll
    for (int k = 0; k < 32; ++k) {
      double a[4], bv[4];
#pragma unroll
      for (int i = 0; i < 4; ++i) a[i] = Ea[bi + i][k];
#pragma unroll
      for (int j = 0; j < 4; ++j) bv[j] = Eb[bj + j][k];
#pragma unroll
      for (int i = 0; i < 4; ++i)
#pragma unroll
        for (int j = 0; j < 4; ++j) s[i][j] = fma(a[i], bv[j], s[i][j]);
    }

#pragma unroll
    for (int i = 0; i < 4; ++i)
#pragma unroll
      for (int j = 0; j < 4; ++j) {
        int gi = i0 + bi + i, gj = jj0 + bj + j;
        if (gi < S && gj < S && gi >= gj)
          A[(size_t)(o + gi) * DD + (o + gj)] -= s[i][j];
      }
  }
}

// ---------------------------------------------------------------------------
// K5: out[b, triu(i,j)] = (i==j) ? 2*log(L[ii]) : L[j][i], fp32, coalesced.
// ---------------------------------------------------------------------------
__global__ __launch_bounds__(256) void k_out(const double* __restrict__ cov,
                                             float* __restrict__ out) {
  const int b = blockIdx.y;
  int t = blockIdx.x;
  int ti = 0, tj = t;
  while (tj >= 4 - ti) {
    tj -= (4 - ti);
    ti++;
  }
  tj += ti;
  const int tid = threadIdx.x;
  const double* A = cov + (size_t)b * DD * DD;

  __shared__ float S[64][65];
  for (int e = tid; e < 4096; e += 256) {
    int jj = e >> 6, ii = e & 63;
    S[jj][ii] = (float)A[(size_t)(tj * 64 + jj) * DD + ti * 64 + ii];
  }
  __syncthreads();

  for (int e = tid; e < 4096; e += 256) {
    int ii = e >> 6, jj = e & 63;
    int i = ti * 64 + ii, j = tj * 64 + jj;
    if (j < i) continue;
    float v = S[jj][ii];
    if (i == j) v = 2.0f * logf(v);
    int off = i * DD - (i * (i - 1)) / 2 + (j - i);
    out[(size_t)b * 32896 + off] = v;
  }
}

extern "C" void kernel_launch(void* const* d_in, const int* in_sizes, int n_in,
                              void* d_out, int out_size, void* d_ws,
                              size_t ws_size, hipStream_t stream) {
  const float* x = (const float*)d_in[0];
  const float* w = (const float*)d_in[1];
  const float* gamma = (const float*)d_in[2];
  const float* beta = (const float*)d_in[3];
  const float* rmean = (const float*)d_in[4];
  const float* rvar = (const float*)d_in[5];
  float* out = (float*)d_out;

  char* ws = (char*)d_ws;
  float* yt = (float*)ws;                           // 12,845,056 B
  double* mean = (double*)(ws + 12845056);          //    131,072 B
  double* cov = (double*)(ws + 12845056 + 131072);  // 33,554,432 B

  k_conv<<<dim3(NTOT / 64, DD / 64), 256, 0, stream>>>(x, w, gamma, beta,
                                                       rmean, rvar, yt);
  k_means<<<BB, 256, 0, stream>>>(yt, mean);
  k_cov<<<dim3(BB, 10), 256, 0, stream>>>(yt, mean, cov);
  for (int kb = 0; kb < 8; ++kb) {
    // sibling tiles cover region cols >= 32*kb+32 with panel(kb-1)'s update
    int ntiles = 0;
    if (kb > 0) {
      int S = DD - (kb * 32 + 32);
      if (S > 0) {
        int nt = (S + 63) / 64;
        ntiles = nt * (nt + 1) / 2;
      }
    }
    k_panel2<<<dim3(BB, 1 + ntiles), 256, 0, stream>>>(cov, kb);
  }
  k_out<<<dim3(10, BB), 256, 0, stream>>>(cov, out);
}

// Round 6
// 627.856 us; speedup vs baseline: 1.6093x; 1.1474x over previous
//
#include <hip/hip_runtime.h>
#include <math.h>

#define BB 64
#define CC 2048
#define MM 196
#define DD 256
#define NTOT (BB * MM)  // 12544

typedef __attribute__((ext_vector_type(8))) short short8;
typedef __attribute__((ext_vector_type(4))) short short4v;
typedef __attribute__((ext_vector_type(4))) unsigned short ushort4v;
typedef __attribute__((ext_vector_type(4))) float f32x4;

__device__ __forceinline__ unsigned short bf16_rne(float f) {
  unsigned int u = __float_as_uint(f);
  unsigned int r = u + 0x7FFFu + ((u >> 16) & 1u);
  return (unsigned short)(r >> 16);
}

// ---------------------------------------------------------------------------
// K0: prep — split W into bf16 hi/lo (wh+wl), precompute BN scale/shift.
// ---------------------------------------------------------------------------
__global__ __launch_bounds__(256) void k_prep(
    const float* __restrict__ w, const float* __restrict__ gamma,
    const float* __restrict__ beta, const float* __restrict__ rmean,
    const float* __restrict__ rvar, unsigned short* __restrict__ wh,
    unsigned short* __restrict__ wl, float* __restrict__ sclv,
    float* __restrict__ sftv) {
  const int e0 = (blockIdx.x * 256 + threadIdx.x) * 4;
  f32x4 v = *(const f32x4*)(w + e0);
  ushort4v h, l;
#pragma unroll
  for (int i = 0; i < 4; ++i) {
    unsigned short hb = bf16_rne(v[i]);
    float hf = __uint_as_float((unsigned int)hb << 16);
    h[i] = hb;
    l[i] = bf16_rne(v[i] - hf);
  }
  *(ushort4v*)(wh + e0) = h;
  *(ushort4v*)(wl + e0) = l;
  if (blockIdx.x == 0 && threadIdx.x < DD) {
    int d = threadIdx.x;
    float s = gamma[d] / sqrtf(rvar[d] + 1e-5f);
    sclv[d] = s;
    sftv[d] = beta[d] - rmean[d] * s;
  }
}

// ---------------------------------------------------------------------------
// K1: conv+BN+ReLU via bf16 split-3 MFMA (hh + hl + lh), fp32 accumulate.
// Tile: full D=256 x 64 n per block (196 blocks), wave w owns d-range
// w*64..w*64+63 (4 MFMA d-subtiles) x all 4 n-subtiles.
// W frags direct from global (prepped bf16, reg-prefetch); X staged
// fp32->LDS with on-the-fly hi/lo split.  Output TRANSPOSED yt[b][m][d].
// ---------------------------------------------------------------------------
__global__ __launch_bounds__(256, 2) void k_conv(
    const float* __restrict__ x, const unsigned short* __restrict__ wh,
    const unsigned short* __restrict__ wl, const float* __restrict__ sclv,
    const float* __restrict__ sftv, float* __restrict__ yt) {
  const int tid = threadIdx.x;
  const int wid = tid >> 6, lane = tid & 63;
  const int quad = lane >> 4, l16 = lane & 15;
  const int n0 = blockIdx.x * 64;

  __shared__ unsigned short Xh[64][36];
  __shared__ unsigned short Xl[64][36];

  f32x4 acc[4][4];
#pragma unroll
  for (int i = 0; i < 4; ++i)
#pragma unroll
    for (int j = 0; j < 4; ++j) acc[i][j] = (f32x4)0.f;

  const int nX = tid & 63, kq = tid >> 6;
  const int gn = n0 + nX;
  const int bX = gn / MM, mX = gn - bX * MM;
  const float* xp = x + (size_t)bX * CC * MM + mX;

  float xr[8];
#pragma unroll
  for (int p = 0; p < 8; ++p) xr[p] = xp[(size_t)(kq * 8 + p) * MM];

  size_t aoff[4];
#pragma unroll
  for (int ds = 0; ds < 4; ++ds)
    aoff[ds] = (size_t)(wid * 64 + ds * 16 + l16) * CC + quad * 8;

  short8 Ah[4], Al[4], Ah2[4], Al2[4];
#pragma unroll
  for (int ds = 0; ds < 4; ++ds) {
    Ah[ds] = *(const short8*)(wh + aoff[ds]);
    Al[ds] = *(const short8*)(wl + aoff[ds]);
  }

  for (int c = 0; c < 64; ++c) {
    const int k0 = c * 32;
    __syncthreads();
    {
      ushort4v h0, h1, l0, l1;
#pragma unroll
      for (int p = 0; p < 4; ++p) {
        unsigned short hb = bf16_rne(xr[p]);
        float hf = __uint_as_float((unsigned int)hb << 16);
        h0[p] = hb;
        l0[p] = bf16_rne(xr[p] - hf);
      }
#pragma unroll
      for (int p = 0; p < 4; ++p) {
        unsigned short hb = bf16_rne(xr[4 + p]);
        float hf = __uint_as_float((unsigned int)hb << 16);
        h1[p] = hb;
        l1[p] = bf16_rne(xr[4 + p] - hf);
      }
      *(ushort4v*)&Xh[nX][kq * 8] = h0;
      *(ushort4v*)&Xh[nX][kq * 8 + 4] = h1;
      *(ushort4v*)&Xl[nX][kq * 8] = l0;
      *(ushort4v*)&Xl[nX][kq * 8 + 4] = l1;
    }
    __syncthreads();
    if (c < 63) {
#pragma unroll
      for (int p = 0; p < 8; ++p)
        xr[p] = xp[(size_t)(k0 + 32 + kq * 8 + p) * MM];
#pragma unroll
      for (int ds = 0; ds < 4; ++ds) {
        Ah2[ds] = *(const short8*)(wh + aoff[ds] + k0 + 32);
        Al2[ds] = *(const short8*)(wl + aoff[ds] + k0 + 32);
      }
    }
#pragma unroll
    for (int ns = 0; ns < 4; ++ns) {
      const unsigned short* bp = &Xh[ns * 16 + l16][quad * 8];
      short4v b0 = *(const short4v*)bp;
      short4v b1 = *(const short4v*)(bp + 4);
      short8 Bh = __builtin_shufflevector(b0, b1, 0, 1, 2, 3, 4, 5, 6, 7);
      const unsigned short* bq = &Xl[ns * 16 + l16][quad * 8];
      short4v c0 = *(const short4v*)bq;
      short4v c1 = *(const short4v*)(bq + 4);
      short8 Bl = __builtin_shufflevector(c0, c1, 0, 1, 2, 3, 4, 5, 6, 7);
#pragma unroll
      for (int ds = 0; ds < 4; ++ds) {
        acc[ds][ns] = __builtin_amdgcn_mfma_f32_16x16x32_bf16(
            Ah[ds], Bh, acc[ds][ns], 0, 0, 0);
        acc[ds][ns] = __builtin_amdgcn_mfma_f32_16x16x32_bf16(
            Ah[ds], Bl, acc[ds][ns], 0, 0, 0);
        acc[ds][ns] = __builtin_amdgcn_mfma_f32_16x16x32_bf16(
            Al[ds], Bh, acc[ds][ns], 0, 0, 0);
      }
    }
#pragma unroll
    for (int ds = 0; ds < 4; ++ds) {
      Ah[ds] = Ah2[ds];
      Al[ds] = Al2[ds];
    }
  }

  // epilogue: BN + ReLU, store yt[b][m][d] (float4 per lane, d contiguous)
#pragma unroll
  for (int ds = 0; ds < 4; ++ds) {
    const int dbase = wid * 64 + ds * 16 + quad * 4;
    f32x4 s4 = *(const f32x4*)(sclv + dbase);
    f32x4 f4 = *(const f32x4*)(sftv + dbase);
#pragma unroll
    for (int ns = 0; ns < 4; ++ns) {
      const int n = n0 + ns * 16 + l16;
      const int b = n / MM, m = n - b * MM;
      f32x4 o;
#pragma unroll
      for (int r = 0; r < 4; ++r) {
        float v = fmaf(acc[ds][ns][r], s4[r], f4[r]);
        o[r] = v > 0.f ? v : 0.f;
      }
      *(f32x4*)(yt + ((size_t)b * MM + m) * DD + dbase) = o;
    }
  }
}

// ---------------------------------------------------------------------------
// K2: per-(b,d) mean over m in fp64.
// ---------------------------------------------------------------------------
__global__ __launch_bounds__(256) void k_means(const float* __restrict__ yt,
                                               double* __restrict__ mean) {
  const int b = blockIdx.x;
  const int d = threadIdx.x;
  const float* p = yt + (size_t)b * MM * DD + d;
  double s0 = 0, s1 = 0, s2 = 0, s3 = 0;
  for (int m = 0; m < MM; m += 4) {
    s0 += (double)p[(size_t)(m + 0) * DD];
    s1 += (double)p[(size_t)(m + 1) * DD];
    s2 += (double)p[(size_t)(m + 2) * DD];
    s3 += (double)p[(size_t)(m + 3) * DD];
  }
  mean[b * DD + d] = (s0 + s1 + s2 + s3) * (1.0 / MM);
}

// ---------------------------------------------------------------------------
// K3: cov[b] = (Y-mu)(Y-mu)^T / M + eps*I  in fp64, lower tiles mirrored
// (R4-proven VALU version).
// ---------------------------------------------------------------------------
__global__ __launch_bounds__(256) void k_cov(const float* __restrict__ yt,
                                             const double* __restrict__ mean,
                                             double* __restrict__ cov) {
  const int b = blockIdx.x;
  const int t = blockIdx.y;
  const int ti = (t < 1) ? 0 : (t < 3) ? 1 : (t < 6) ? 2 : 3;
  const int tj = t - (ti * (ti + 1)) / 2;
  const int i0 = ti * 64, j0 = tj * 64;
  const int tid = threadIdx.x;
  const int tx = tid & 15, ty = tid >> 4;

  __shared__ double As[32][66];
  __shared__ double Bs[32][66];

  double acc[4][4];
#pragma unroll
  for (int i = 0; i < 4; ++i)
#pragma unroll
    for (int j = 0; j < 4; ++j) acc[i][j] = 0.0;

  const int dl = tid & 63, kl = tid >> 6;
  const double mA = mean[b * DD + i0 + dl];
  const double mB = mean[b * DD + j0 + dl];
  const float* ybase = yt + (size_t)b * MM * DD;

  for (int k0 = 0; k0 < MM; k0 += 32) {
    __syncthreads();
#pragma unroll
    for (int p = 0; p < 8; ++p) {
      int k = kl + p * 4;
      int m = k0 + k;
      double av = 0.0, bv = 0.0;
      if (m < MM) {
        av = (double)ybase[(size_t)m * DD + i0 + dl] - mA;
        bv = (double)ybase[(size_t)m * DD + j0 + dl] - mB;
      }
      As[k][dl] = av;
      Bs[k][dl] = bv;
    }
    __syncthreads();
#pragma unroll
    for (int k = 0; k < 32; ++k) {
      double a[4], bv[4];
#pragma unroll
      for (int i = 0; i < 4; ++i) a[i] = As[k][ty * 4 + i];
#pragma unroll
      for (int j = 0; j < 4; ++j) bv[j] = Bs[k][tx * 4 + j];
#pragma unroll
      for (int i = 0; i < 4; ++i)
#pragma unroll
        for (int j = 0; j < 4; ++j) acc[i][j] = fma(a[i], bv[j], acc[i][j]);
    }
  }

  double* cb = cov + (size_t)b * DD * DD;
#pragma unroll
  for (int i = 0; i < 4; ++i) {
#pragma unroll
    for (int j = 0; j < 4; ++j) {
      int gi = i0 + ty * 4 + i, gj = j0 + tx * 4 + j;
      double v = acc[i][j] * (1.0 / MM);
      if (gi == gj) v += 1e-6;
      cb[(size_t)gi * DD + gj] = v;
      if (ti != tj) cb[(size_t)gj * DD + gi] = v;
    }
  }
}

// ---------------------------------------------------------------------------
// K4: lookahead Cholesky step kb (R4-proven verbatim).
// ---------------------------------------------------------------------------
__global__ __launch_bounds__(256) void k_panel2(double* __restrict__ cov,
                                                int kb) {
  const int b = blockIdx.x;
  double* A = cov + (size_t)b * DD * DD;
  const int j0 = kb * 32;
  const int tid = threadIdx.x;

  __shared__ double Sp[256][33];
  __shared__ double Lp[224][33];
  __shared__ double L11s[32][33];
  __shared__ double rpivs[32];

  if (blockIdx.y == 0) {
    const int R = DD - j0;
    const int pj = j0 - 32;

    for (int e = tid; e < R * 32; e += 256) {
      int r = e >> 5, c = e & 31;
      Sp[r][c] = A[(size_t)(j0 + r) * DD + j0 + c];
      if (kb > 0) Lp[r][c] = A[(size_t)(j0 + r) * DD + pj + c];
    }
    __syncthreads();

    if (kb > 0) {
      const int cg = tid & 7;
      const int rg = tid >> 3;
      const int c0 = cg * 4;
      for (int r = rg; r < R; r += 32) {
        double a0 = 0, a1 = 0, a2 = 0, a3 = 0;
#pragma unroll
        for (int p = 0; p < 32; ++p) {
          double lr = Lp[r][p];
          a0 = fma(lr, Lp[c0 + 0][p], a0);
          a1 = fma(lr, Lp[c0 + 1][p], a1);
          a2 = fma(lr, Lp[c0 + 2][p], a2);
          a3 = fma(lr, Lp[c0 + 3][p], a3);
        }
        Sp[r][c0 + 0] -= a0;
        Sp[r][c0 + 1] -= a1;
        Sp[r][c0 + 2] -= a2;
        Sp[r][c0 + 3] -= a3;
      }
    }
    __syncthreads();

    if (tid < 32) {
      double r[32];
#pragma unroll
      for (int k = 0; k < 32; ++k) r[k] = Sp[tid][k];
      double rpkeep = 0.0;
#pragma unroll
      for (int j = 0; j < 32; ++j) {
        double dj = __shfl(r[j], j);
        double piv = sqrt(dj);
        double rp = 1.0 / piv;
        if (tid == j) {
          r[j] = piv;
          rpkeep = rp;
        } else {
          r[j] = r[j] * rp;
        }
        double lij = r[j];
#pragma unroll
        for (int k = j + 1; k < 32; ++k) {
          double ck = __shfl(lij, k);
          r[k] -= lij * ck;
        }
      }
#pragma unroll
      for (int k = 0; k < 32; ++k) L11s[tid][k] = (k <= tid) ? r[k] : 0.0;
      rpivs[tid] = rpkeep;
      for (int k = 0; k <= tid; ++k)
        A[(size_t)(j0 + tid) * DD + j0 + k] = r[k];
    }
    __syncthreads();

    const int T = R - 32;
    if (tid < T) {
      double q[32];
#pragma unroll
      for (int k = 0; k < 32; ++k) q[k] = Sp[32 + tid][k];
#pragma unroll
      for (int j = 0; j < 32; ++j) {
        double s = q[j];
#pragma unroll
        for (int k = 0; k < 32; ++k)
          if (k < j) s -= q[k] * L11s[j][k];
        q[j] = s * rpivs[j];
      }
      double* dst = &A[(size_t)(j0 + 32 + tid) * DD + j0];
#pragma unroll
      for (int k = 0; k < 32; ++k) dst[k] = q[k];
    }
  } else {
    const int o = j0 + 32;
    const int S = DD - o;
    const int pj = j0 - 32;
    int tI = 0, tJ = (int)blockIdx.y - 1;
    while (tJ > tI) {
      tJ -= (tI + 1);
      tI++;
    }
    const int i0 = tI * 64, jj0 = tJ * 64;
    const int txl = tid & 15, tyl = tid >> 4;

    double(*Ea)[33] = (double(*)[33])(&Lp[0][0]);
    double(*Eb)[33] = (double(*)[33])(&Lp[64][0]);

    for (int e = tid; e < 64 * 32; e += 256) {
      int r = e >> 5, c = e & 31;
      Ea[r][c] = (i0 + r < S) ? A[(size_t)(o + i0 + r) * DD + pj + c] : 0.0;
      Eb[r][c] = (jj0 + r < S) ? A[(size_t)(o + jj0 + r) * DD + pj + c] : 0.0;
    }
    __syncthreads();

    double s[4][4];
#pragma unroll
    for (int i = 0; i < 4; ++i)
#pragma unroll
      for (int j = 0; j < 4; ++j) s[i][j] = 0.0;

    const int bi = tyl * 4, bj = txl * 4;
#pragma unroll
    for (int k = 0; k < 32; ++k) {
      double a[4], bv[4];
#pragma unroll
      for (int i = 0; i < 4; ++i) a[i] = Ea[bi + i][k];
#pragma unroll
      for (int j = 0; j < 4; ++j) bv[j] = Eb[bj + j][k];
#pragma unroll
      for (int i = 0; i < 4; ++i)
#pragma unroll
        for (int j = 0; j < 4; ++j) s[i][j] = fma(a[i], bv[j], s[i][j]);
    }

#pragma unroll
    for (int i = 0; i < 4; ++i)
#pragma unroll
      for (int j = 0; j < 4; ++j) {
        int gi = i0 + bi + i, gj = jj0 + bj + j;
        if (gi < S && gj < S && gi >= gj)
          A[(size_t)(o + gi) * DD + (o + gj)] -= s[i][j];
      }
  }
}

// ---------------------------------------------------------------------------
// K5: out[b, triu(i,j)] = (i==j) ? 2*log(L[ii]) : L[j][i], fp32, coalesced.
// ---------------------------------------------------------------------------
__global__ __launch_bounds__(256) void k_out(const double* __restrict__ cov,
                                             float* __restrict__ out) {
  const int b = blockIdx.y;
  int t = blockIdx.x;
  int ti = 0, tj = t;
  while (tj >= 4 - ti) {
    tj -= (4 - ti);
    ti++;
  }
  tj += ti;
  const int tid = threadIdx.x;
  const double* A = cov + (size_t)b * DD * DD;

  __shared__ float S[64][65];
  for (int e = tid; e < 4096; e += 256) {
    int jj = e >> 6, ii = e & 63;
    S[jj][ii] = (float)A[(size_t)(tj * 64 + jj) * DD + ti * 64 + ii];
  }
  __syncthreads();

  for (int e = tid; e < 4096; e += 256) {
    int ii = e >> 6, jj = e & 63;
    int i = ti * 64 + ii, j = tj * 64 + jj;
    if (j < i) continue;
    float v = S[jj][ii];
    if (i == j) v = 2.0f * logf(v);
    int off = i * DD - (i * (i - 1)) / 2 + (j - i);
    out[(size_t)b * 32896 + off] = v;
  }
}

extern "C" void kernel_launch(void* const* d_in, const int* in_sizes, int n_in,
                              void* d_out, int out_size, void* d_ws,
                              size_t ws_size, hipStream_t stream) {
  const float* x = (const float*)d_in[0];
  const float* w = (const float*)d_in[1];
  const float* gamma = (const float*)d_in[2];
  const float* beta = (const float*)d_in[3];
  const float* rmean = (const float*)d_in[4];
  const float* rvar = (const float*)d_in[5];
  float* out = (float*)d_out;

  char* ws = (char*)d_ws;
  float* yt = (float*)ws;                           // 12,845,056 B
  double* mean = (double*)(ws + 12845056);          //    131,072 B
  double* cov = (double*)(ws + 12845056 + 131072);  // 33,554,432 B
  // alias W-prep buffers into cov (consumed by k_conv before cov is written)
  unsigned short* wh = (unsigned short*)cov;  // 1,048,576 B
  unsigned short* wl = wh + (DD * CC);        // 1,048,576 B
  float* sclv = (float*)(wl + (DD * CC));     //     1,024 B
  float* sftv = sclv + DD;                    //     1,024 B

  k_prep<<<512, 256, 0, stream>>>(w, gamma, beta, rmean, rvar, wh, wl, sclv,
                                  sftv);
  k_conv<<<NTOT / 64, 256, 0, stream>>>(x, wh, wl, sclv, sftv, yt);
  k_means<<<BB, 256, 0, stream>>>(yt, mean);
  k_cov<<<dim3(BB, 10), 256, 0, stream>>>(yt, mean, cov);
  for (int kb = 0; kb < 8; ++kb) {
    int ntiles = 0;
    if (kb > 0) {
      int S = DD - (kb * 32 + 32);
      if (S > 0) {
        int nt = (S + 63) / 64;
        ntiles = nt * (nt + 1) / 2;
      }
    }
    k_panel2<<<dim3(BB, 1 + ntiles), 256, 0, stream>>>(cov, kb);
  }
  k_out<<<dim3(10, BB), 256, 0, stream>>>(cov, out);
}